// Round 1
// baseline (51.958 us; speedup 1.0000x reference)
//
#include <hip/hip_runtime.h>
#include <hip/hip_bf16.h>

// SparseProtoLinear: B=4,T=2048,H=16,D=64,P=8 -> S=131072 tokens.
// d_out = [y (S*64) | logits (S*8) | mask (S*8)], all fp32.
//
// Fused kernel: 128 tokens/block (4 waves), dense over 8 experts.
//  Phase 1: load X fp32 (coalesced f32x4), fp32 logits via wave-uniform
//           scalar proto loads, X -> bf16 XOR-swizzled LDS tile.
//  Per expert: stage W1/W2 fp32->bf16 LDS (swizzled), GEMM1 (mfma
//           16x16x32 bf16), silu, Hmid->LDS, GEMM2, weighted accumulate.

typedef __attribute__((ext_vector_type(8))) short short8;
typedef __attribute__((ext_vector_type(4))) float f32x4;
typedef __attribute__((ext_vector_type(4))) unsigned int u32x4;
typedef __attribute__((ext_vector_type(2))) unsigned int u32x2;

#define NEXP 8
#define DH 64
#define BT 128
#define THREADS 256

#define OFF_X  0          // 128 rows * 128B = 16384
#define OFF_W1 16384      // 64 * 128B = 8192
#define OFF_W2 24576      // 64 * 128B = 8192
#define OFF_H  32768      // 4 waves * 32 * 128B = 16384 (phase1: partial scratch)
#define OFF_WT 49152      // 128 * 8 * 4B = 4096
#define LDS_BYTES 53248   // 52 KB -> 3 blocks/CU

__device__ __forceinline__ int swz(int row, int c) {
    // XOR-swizzle: breaks the 128B-row-stride same-bank pattern (G4).
    return row * 128 + (c ^ ((row & 7) << 4));
}
__device__ __forceinline__ unsigned int f2bf_u(float f) {
    // RTNE float -> bf16 (no NaN inputs here)
    unsigned int u = __builtin_bit_cast(unsigned int, f);
    return (u + 0x7fffu + ((u >> 16) & 1u)) >> 16;
}

__global__ __launch_bounds__(THREADS, 3)
void spl_kernel(const float* __restrict__ x, const float* __restrict__ proto,
                const float* __restrict__ gate, const float* __restrict__ w1,
                const float* __restrict__ w2, float* __restrict__ y_out,
                float* __restrict__ logits_out, float* __restrict__ mask_out)
{
    __shared__ __align__(16) char smem[LDS_BYTES];
    const int tid = threadIdx.x;
    const int tok0 = blockIdx.x * BT;

    // ---------------- Phase 1: X load + logits ----------------
    const int row = tid & 127;                                   // token (local)
    const int half = __builtin_amdgcn_readfirstlane(tid >> 7);   // wave-uniform half of D

    const float* xg = x + (size_t)(tok0 + row) * DH + half * 32;
    float xv[32];
#pragma unroll
    for (int j = 0; j < 8; ++j) {
        f32x4 v = *reinterpret_cast<const f32x4*>(xg + j * 4);
#pragma unroll
        for (int i = 0; i < 4; ++i) xv[j * 4 + i] = v[i];
    }
    // X -> bf16 swizzled tile
#pragma unroll
    for (int j = 0; j < 4; ++j) {
        u32x4 pk;
#pragma unroll
        for (int i = 0; i < 4; ++i)
            pk[i] = f2bf_u(xv[j * 8 + i * 2]) | (f2bf_u(xv[j * 8 + i * 2 + 1]) << 16);
        *reinterpret_cast<u32x4*>(smem + OFF_X + swz(row, half * 64 + j * 16)) = pk;
    }
    // partial logits (fp32). proto address is wave-uniform -> s_load broadcast.
    float part[NEXP];
#pragma unroll
    for (int p = 0; p < NEXP; ++p) {
        const float* pr = proto + p * DH + half * 32;
        float acc = 0.f;
#pragma unroll
        for (int d = 0; d < 32; ++d) acc += xv[d] * pr[d];
        part[p] = acc;
    }
    if (half) {  // waves 2-3 publish partials
        f32x4 a = { part[0], part[1], part[2], part[3] };
        f32x4 b = { part[4], part[5], part[6], part[7] };
        *reinterpret_cast<f32x4*>(smem + OFF_H + row * 32) = a;
        *reinterpret_cast<f32x4*>(smem + OFF_H + row * 32 + 16) = b;
    }
    __syncthreads();
    if (!half) { // waves 0-1 finalize logits/mask/weight
        f32x4 pa = *reinterpret_cast<const f32x4*>(smem + OFF_H + row * 32);
        f32x4 pb = *reinterpret_cast<const f32x4*>(smem + OFF_H + row * 32 + 16);
        float* wtL = reinterpret_cast<float*>(smem + OFF_WT);
        f32x4 lg0, lg1, mk0, mk1;
#pragma unroll
        for (int p = 0; p < NEXP; ++p) {
            float other = (p < 4) ? pa[p] : pb[p - 4];
            float l = (part[p] + other) * 0.125f - gate[p];
            float m = fmaxf(l, 0.f);
            if (p < 4) { lg0[p] = l; mk0[p] = m; } else { lg1[p - 4] = l; mk1[p - 4] = m; }
            wtL[row * NEXP + p] = (m > 1e-6f) ? m : 0.f;
        }
        size_t lb = (size_t)(tok0 + row) * NEXP;
        *reinterpret_cast<f32x4*>(logits_out + lb) = lg0;
        *reinterpret_cast<f32x4*>(logits_out + lb + 4) = lg1;
        *reinterpret_cast<f32x4*>(mask_out + lb) = mk0;
        *reinterpret_cast<f32x4*>(mask_out + lb + 4) = mk1;
    }

    // ---------------- Phase 2: expert loop ----------------
    const int lane = tid & 63;
    const int wv = __builtin_amdgcn_readfirstlane(tid >> 6);
    const int fr = lane & 15;   // MFMA fragment row/col index
    const int fg = lane >> 4;   // lane group 0..3
    char* const sX = smem + OFF_X;
    char* const sW1 = smem + OFF_W1;
    char* const sW2 = smem + OFF_W2;
    char* const sH = smem + OFF_H + wv * 4096;   // per-wave Hmid (32x64 bf16)
    const float* const wtL = reinterpret_cast<const float*>(smem + OFF_WT);

    const f32x4 vzero = { 0.f, 0.f, 0.f, 0.f };
    f32x4 yacc[2][4];
#pragma unroll
    for (int m = 0; m < 2; ++m)
#pragma unroll
        for (int n = 0; n < 4; ++n) yacc[m][n] = vzero;

    for (int p = 0; p < NEXP; ++p) {
        __syncthreads();   // prev expert's W reads done (and phase1 done, p=0)
        // --- stage W1,W2: fp32 -> bf16, swizzled. coalesced 1KB/wave loads ---
        const float* w1p = w1 + p * (DH * DH);
        const float* w2p = w2 + p * (DH * DH);
#pragma unroll
        for (int j = 0; j < 4; ++j) {
            const int o = j * 16 + (tid >> 4);
            const int c = (tid & 15) * 8;
            f32x4 v = *reinterpret_cast<const f32x4*>(w1p + j * 1024 + tid * 4);
            u32x2 pk;
            pk[0] = f2bf_u(v[0]) | (f2bf_u(v[1]) << 16);
            pk[1] = f2bf_u(v[2]) | (f2bf_u(v[3]) << 16);
            *reinterpret_cast<u32x2*>(sW1 + swz(o, c)) = pk;
            f32x4 u = *reinterpret_cast<const f32x4*>(w2p + j * 1024 + tid * 4);
            u32x2 qk;
            qk[0] = f2bf_u(u[0]) | (f2bf_u(u[1]) << 16);
            qk[1] = f2bf_u(u[2]) | (f2bf_u(u[3]) << 16);
            *reinterpret_cast<u32x2*>(sW2 + swz(o, c)) = qk;
        }
        __syncthreads();

        // --- GEMM1: Hmid[32x64] = X[32x64] @ W1^T ---
        short8 afr[2][2], bfr[4][2];
#pragma unroll
        for (int m = 0; m < 2; ++m)
#pragma unroll
            for (int k = 0; k < 2; ++k)
                afr[m][k] = *reinterpret_cast<const short8*>(
                    sX + swz(wv * 32 + m * 16 + fr, k * 64 + fg * 16));
#pragma unroll
        for (int n = 0; n < 4; ++n)
#pragma unroll
            for (int k = 0; k < 2; ++k)
                bfr[n][k] = *reinterpret_cast<const short8*>(
                    sW1 + swz(n * 16 + fr, k * 64 + fg * 16));
        f32x4 acc[2][4];
#pragma unroll
        for (int m = 0; m < 2; ++m)
#pragma unroll
            for (int n = 0; n < 4; ++n) acc[m][n] = vzero;
#pragma unroll
        for (int k = 0; k < 2; ++k)
#pragma unroll
            for (int m = 0; m < 2; ++m)
#pragma unroll
                for (int n = 0; n < 4; ++n)
                    acc[m][n] = __builtin_amdgcn_mfma_f32_16x16x32_bf16(
                        afr[m][k], bfr[n][k], acc[m][n], 0, 0, 0);

        // --- silu -> bf16 -> per-wave Hmid LDS ---
        // C/D layout: col = n*16 + fr, row = m*16 + fg*4 + r   (m89-verified)
#pragma unroll
        for (int m = 0; m < 2; ++m)
#pragma unroll
            for (int n = 0; n < 4; ++n)
#pragma unroll
                for (int r = 0; r < 4; ++r) {
                    float h = acc[m][n][r];
                    float e = __expf(-h);
                    float s = h * __builtin_amdgcn_rcpf(1.f + e);
                    *reinterpret_cast<unsigned short*>(
                        sH + swz(m * 16 + fg * 4 + r, (n * 16 + fr) * 2)) =
                        (unsigned short)f2bf_u(s);
                }
        __syncthreads();

        // --- GEMM2: Out[32x64] = Hmid @ W2^T ---
        short8 a2[2][2], b2[4][2];
#pragma unroll
        for (int m = 0; m < 2; ++m)
#pragma unroll
            for (int k = 0; k < 2; ++k)
                a2[m][k] = *reinterpret_cast<const short8*>(
                    sH + swz(m * 16 + fr, k * 64 + fg * 16));
#pragma unroll
        for (int n = 0; n < 4; ++n)
#pragma unroll
            for (int k = 0; k < 2; ++k)
                b2[n][k] = *reinterpret_cast<const short8*>(
                    sW2 + swz(n * 16 + fr, k * 64 + fg * 16));
        f32x4 o2[2][4];
#pragma unroll
        for (int m = 0; m < 2; ++m)
#pragma unroll
            for (int n = 0; n < 4; ++n) o2[m][n] = vzero;
#pragma unroll
        for (int k = 0; k < 2; ++k)
#pragma unroll
            for (int m = 0; m < 2; ++m)
#pragma unroll
                for (int n = 0; n < 4; ++n)
                    o2[m][n] = __builtin_amdgcn_mfma_f32_16x16x32_bf16(
                        a2[m][k], b2[n][k], o2[m][n], 0, 0, 0);

        // --- weighted accumulate into y ---
#pragma unroll
        for (int m = 0; m < 2; ++m)
#pragma unroll
            for (int r = 0; r < 4; ++r) {
                float wt = wtL[(wv * 32 + m * 16 + fg * 4 + r) * NEXP + p];
#pragma unroll
                for (int n = 0; n < 4; ++n)
                    yacc[m][n][r] += wt * o2[m][n][r];
            }
    }

    // ---------------- write y ----------------
#pragma unroll
    for (int m = 0; m < 2; ++m)
#pragma unroll
        for (int r = 0; r < 4; ++r) {
            size_t gr = (size_t)(tok0 + wv * 32 + m * 16 + fg * 4 + r) * DH;
#pragma unroll
            for (int n = 0; n < 4; ++n)
                y_out[gr + n * 16 + fr] = yacc[m][n][r];
        }
}

extern "C" void kernel_launch(void* const* d_in, const int* in_sizes, int n_in,
                              void* d_out, int out_size, void* d_ws, size_t ws_size,
                              hipStream_t stream) {
    (void)n_in; (void)out_size; (void)d_ws; (void)ws_size;
    const float* x     = (const float*)d_in[0];
    const float* proto = (const float*)d_in[1];
    const float* gate  = (const float*)d_in[2];
    const float* w1    = (const float*)d_in[3];
    const float* w2    = (const float*)d_in[4];
    float* y = (float*)d_out;
    const int S = in_sizes[0] / DH;                 // 131072
    float* logits = y + (size_t)S * DH;
    float* mask   = logits + (size_t)S * NEXP;
    spl_kernel<<<S / BT, THREADS, 0, stream>>>(x, proto, gate, w1, w2, y, logits, mask);
}